// Round 5
// baseline (502.591 us; speedup 1.0000x reference)
//
#include <hip/hip_runtime.h>
#include <hip/hip_fp16.h>

#define OUTN 16384
#define BATCH 2048
#define DIM   256
#define NBLK  512

typedef _Float16 half8 __attribute__((ext_vector_type(8)));
typedef float    floatx4 __attribute__((ext_vector_type(4)));
typedef unsigned long long u64;

__device__ __forceinline__ void gl2lds16(const void* g, void* l) {
    __builtin_amdgcn_global_load_lds(
        (const __attribute__((address_space(1))) void*)g,
        (__attribute__((address_space(3))) void*)l, 16, 0, 0);
}

// monotone float->uint map packed with column index (low 32): min(pack) = argmin
__device__ __forceinline__ u64 packkey(float v, int col) {
    unsigned u = __float_as_uint(v);
    u = (u & 0x80000000u) ? ~u : (u | 0x80000000u);
    return ((u64)u << 32) | (unsigned)col;
}
__device__ __forceinline__ float unpackval(u64 p) {
    unsigned u = (unsigned)(p >> 32);
    u = (u & 0x80000000u) ? (u & 0x7fffffffu) : ~u;
    return __uint_as_float(u);
}

// device-scope grid barrier: monotonic counter, all NBLK blocks co-resident.
// __threadfence() (agent scope) both sides handles cross-XCD L2 visibility.
__device__ __forceinline__ void gridbar(unsigned* bar, unsigned target) {
    __syncthreads();
    __threadfence();
    if (threadIdx.x == 0) {
        atomicAdd(bar, 1u);
        while (atomicAdd(bar, 0u) < target) __builtin_amdgcn_s_sleep(2);
    }
    __syncthreads();
    __threadfence();
}

__global__ __launch_bounds__(256, 2) void som_fused(
        const float* __restrict__ x, const float* __restrict__ kern,
        _Float16* __restrict__ xh, _Float16* __restrict__ kT,
        float* __restrict__ kT32, float* __restrict__ colnp,
        float* __restrict__ rown, u64* __restrict__ blockcand,
        int* __restrict__ wta, _Float16* __restrict__ n2h,
        float* __restrict__ out, unsigned* __restrict__ bar) {
    __shared__ __align__(16) char smem[34816];
    int p = blockIdx.x, t = threadIdx.x;

    // ================= phase 0: prep =================
    {
        float (*tile)[65] = (float(*)[65])smem;        // 64x65 fp32
        float* npart = (float*)(smem + 16640);         // 4x64
        int tx = t & 63, ty = t >> 6;
        int j0 = (p >> 1) * 64;
        int dhalf = p & 1, dbase = dhalf * 128;
        float nrm = 0.f;
        for (int pc = 0; pc < 2; pc++) {
            int dc = dbase + pc * 64;
            __syncthreads();
            for (int it = 0; it < 16; it++) {
                int d = dc + ty + it * 4;
                float v = kern[(size_t)d * OUTN + j0 + tx];
                tile[ty + it * 4][tx] = v;
                nrm = fmaf(v, v, nrm);
            }
            __syncthreads();
            for (int c = t; c < 512; c += 256) {       // 64j x 64d, 8-elem chunks
                int j = c >> 3, o8 = (c & 7) * 8;
                half8 h; float vv[8];
                for (int u = 0; u < 8; u++) { vv[u] = tile[o8 + u][j]; h[u] = (_Float16)vv[u]; }
                *(half8*)&kT[(size_t)(j0 + j) * DIM + dc + o8] = h;
                float* kp = &kT32[(size_t)(j0 + j) * DIM + dc + o8];
                *(float4*)kp       = make_float4(vv[0], vv[1], vv[2], vv[3]);
                *(float4*)(kp + 4) = make_float4(vv[4], vv[5], vv[6], vv[7]);
            }
        }
        npart[ty * 64 + tx] = nrm;
        __syncthreads();
        if (t < 64)
            colnp[(size_t)dhalf * OUTN + j0 + t] =
                npart[t] + npart[64 + t] + npart[128 + t] + npart[192 + t];
        __syncthreads();
        for (int q = 0; q < 4; q++) {                  // x rows: 4 per block
            int b = p * 4 + q;
            float v = x[b * DIM + t];
            xh[b * DIM + t] = (_Float16)v;
            float s = v * v;
            for (int off = 32; off; off >>= 1) s += __shfl_down(s, off, 64);
            if ((t & 63) == 0) npart[t >> 6] = s;
            __syncthreads();
            if (t == 0) rown[b] = npart[0] + npart[1] + npart[2] + npart[3];
            __syncthreads();
        }
    }
    gridbar(bar, NBLK);

    // ================= phase 1: GEMM -> candidates + f16 norms2 =================
    {
        int rb = p >> 5, cg = p & 31;                  // 16 row-bands x 32 col-groups
        int row0 = rb * 128;
        int wid = t >> 6, lane = t & 63;
        int wr = wid >> 1, wc = wid & 1;
        int l15 = lane & 15, l4 = lane >> 4;
        int xh7 = l15 & 7;
        _Float16* As = (_Float16*)smem;                // 128x64, XOR-swizzled granules
        _Float16* Bs = (_Float16*)(smem + 16384);
        u64* cand = (u64*)smem;                        // 128 x stride-33 u64 (33792 B)
        _Float16* nb = (_Float16*)smem;                // 128x128 f16 (32768 B)

        for (int cc = 0; cc < 4; cc++) {
            int cb = cg * 4 + cc;
            int col0 = cb * 128;
            floatx4 acc[4][4];
            for (int i = 0; i < 4; i++)
                for (int j = 0; j < 4; j++)
                    acc[i][j] = (floatx4){0.f, 0.f, 0.f, 0.f};

            for (int kt = 0; kt < 4; kt++) {
                int k0 = kt * 64;
                for (int it = 0; it < 4; it++) {
                    int chunk = it * 256 + t;
                    int r = chunk >> 3, gg = chunk & 7;
                    int ksw = (gg ^ (r & 7)) * 8;
                    gl2lds16(&xh[(size_t)(row0 + r) * DIM + k0 + ksw], &As[chunk * 8]);
                    gl2lds16(&kT[(size_t)(col0 + r) * DIM + k0 + ksw], &Bs[chunk * 8]);
                }
                __syncthreads();
                for (int s = 0; s < 2; s++) {
                    int g = s * 4 + l4;
                    int sw = (g ^ xh7) * 8;
                    half8 af[4], bf[4];
                    for (int i = 0; i < 4; i++)
                        af[i] = *(half8*)&As[(wr * 64 + i * 16 + l15) * 64 + sw];
                    for (int j = 0; j < 4; j++)
                        bf[j] = *(half8*)&Bs[(wc * 64 + j * 16 + l15) * 64 + sw];
                    for (int i = 0; i < 4; i++)
                        for (int j = 0; j < 4; j++)
                            acc[i][j] = __builtin_amdgcn_mfma_f32_16x16x32_f16(
                                af[i], bf[j], acc[i][j], 0, 0, 0);
                }
                __syncthreads();
            }

            float cn[4]; int oc[4];
            for (int j = 0; j < 4; j++) {
                oc[j] = col0 + wc * 64 + j * 16 + l15;
                cn[j] = colnp[oc[j]] + colnp[OUTN + oc[j]];
            }
            // candidates: key = coln - 2*dot (row-constant ||x||^2 dropped)
            for (int i = 0; i < 4; i++) {
                for (int r = 0; r < 4; r++) {
                    int row_l = wr * 64 + i * 16 + l4 * 4 + r;
                    u64 best = ~0ull;
                    for (int j = 0; j < 4; j++) {
                        u64 pk = packkey(cn[j] - 2.0f * acc[i][j][r], oc[j]);
                        if (pk < best) best = pk;
                    }
                    cand[row_l * 33 + wc * 16 + l15] = best;
                }
            }
            __syncthreads();
            if (t < 128) {
                u64 m1 = ~0ull, m2 = ~0ull;
                for (int s = 0; s < 32; s++) {
                    u64 v = cand[t * 33 + s];
                    if (v < m1) { m2 = m1; m1 = v; }
                    else if (v < m2) { m2 = v; }
                }
                size_t base = (size_t)(row0 + t) * 256 + cb * 2;
                blockcand[base]     = m1;
                blockcand[base + 1] = m2;
            }
            __syncthreads();
            // f16 norms2 via LDS, vectorized store
            for (int i = 0; i < 4; i++) {
                for (int r = 0; r < 4; r++) {
                    int row_l = wr * 64 + i * 16 + l4 * 4 + r;
                    float rn = rown[row0 + row_l];
                    for (int j = 0; j < 4; j++)
                        nb[row_l * 128 + wc * 64 + j * 16 + l15] =
                            (_Float16)(rn + cn[j] - 2.0f * acc[i][j][r]);
                }
            }
            __syncthreads();
            for (int c = t; c < 2048; c += 256) {
                int r = c >> 4, o8 = (c & 15) * 8;
                *(half8*)&n2h[(size_t)(row0 + r) * OUTN + col0 + o8] =
                    *(half8*)&nb[r * 128 + o8];
            }
            __syncthreads();
        }
    }
    gridbar(bar, 2 * NBLK);

    // ================= phase 2: refine (exact fp32 argmin), 4 rows per block =========
    {
        float* xrow = (float*)smem;                    // 256 fp32
        u64*   red  = (u64*)(smem + 1024);             // 256 u64
        for (int q = 0; q < 4; q++) {
            int b = p * 4 + q;
            xrow[t] = x[b * DIM + t];
            u64 e = blockcand[(size_t)b * 256 + t];
            red[t] = e;
            __syncthreads();
            for (int off = 128; off; off >>= 1) {
                if (t < off) { u64 o = red[t + off]; if (o < red[t]) red[t] = o; }
                __syncthreads();
            }
            float minv = unpackval(red[0]);
            __syncthreads();
            u64 pk = ~0ull;
            if (unpackval(e) <= minv + 0.125f) {
                int j = (int)(e & 0xffffffffu);
                const float* kr = kT32 + (size_t)j * DIM;
                float dot = 0.f;
                for (int d = 0; d < DIM; d++)
                    dot = fmaf(xrow[d], kr[d], dot);
                pk = packkey((colnp[j] + colnp[OUTN + j]) - 2.0f * dot, j);
            }
            red[t] = pk;
            __syncthreads();
            for (int off = 128; off; off >>= 1) {
                if (t < off) { u64 o = red[t + off]; if (o < red[t]) red[t] = o; }
                __syncthreads();
            }
            if (t == 0) wta[b] = (int)(red[0] & 0xffffffffu);
            __syncthreads();
        }
    }
    gridbar(bar, 3 * NBLK);

    // ================= phase 3: gaussian * norms2, disk-gated, 4 rows per block ======
    {
        float* colf = (float*)smem;                    // exp(-t^2/8) table
        if (t < 128) colf[t] = __expf(-0.125f * (float)(t * t));
        __syncthreads();
        for (int q = 0; q < 4; q++) {
            int b = p * 4 + q;
            int w = wta[b];
            int wrr = w >> 7, wcc = w & 127;
            const _Float16* nrow = n2h + (size_t)b * OUTN;
            float* orow = out + (size_t)b * OUTN;
            for (int c = t; c < 2048; c += 256) {      // 128 gr x 16 chunks of 8
                int gr = c >> 4, o8 = (c & 15) * 8;
                int dr = gr - wrr; if (dr < 0) dr = -dr;
                float4 r0 = {0.f, 0.f, 0.f, 0.f}, r1 = {0.f, 0.f, 0.f, 0.f};
                if (dr <= 26) {                        // exp(-0.125*27^2)*n2 < 1e-36 ~ 0
                    float rowf = colf[dr];
                    half8 h = *(const half8*)&nrow[gr * 128 + o8];
                    float res[8];
                    for (int u = 0; u < 8; u++) {
                        int dc = o8 + u - wcc; if (dc < 0) dc = -dc;
                        res[u] = rowf * colf[dc] * fmaxf((float)h[u], 0.f);
                    }
                    r0 = make_float4(res[0], res[1], res[2], res[3]);
                    r1 = make_float4(res[4], res[5], res[6], res[7]);
                }
                *(float4*)&orow[gr * 128 + o8]     = r0;
                *(float4*)&orow[gr * 128 + o8 + 4] = r1;
            }
        }
    }
}

extern "C" void kernel_launch(void* const* d_in, const int* in_sizes, int n_in,
                              void* d_out, int out_size, void* d_ws, size_t ws_size,
                              hipStream_t stream) {
    const float* x    = (const float*)d_in[0];   // (2048, 256) fp32
    const float* kern = (const float*)d_in[1];   // (256, 16384) fp32
    float* out = (float*)d_out;                  // (2048, 16384) fp32
    char* ws = (char*)d_ws;

    // ws: xh 1MB@0 | kT 8MB@1M | kT32 16MB@9M | colnp 128K@25M | rown 8K | wta 8K |
    //     bar 64B | blockcand 4MB@26M | n2h 64MB@32M   (total 96 MB)
    _Float16* xh   = (_Float16*)(ws);
    _Float16* kT   = (_Float16*)(ws + (1u << 20));
    float*    kT32 = (float*)(ws + (9u << 20));
    float*   colnp = (float*)(ws + (25u << 20));
    float*    rown = (float*)(ws + (25u << 20) + (128u << 10));
    int*       wta = (int*)(ws + (25u << 20) + (136u << 10));
    unsigned*  bar = (unsigned*)(ws + (25u << 20) + (144u << 10));
    u64* blockcand = (u64*)(ws + (26u << 20));
    _Float16*  n2h = (_Float16*)(ws + (32u << 20));

    hipMemsetAsync(bar, 0, 64, stream);
    som_fused<<<NBLK, 256, 0, stream>>>(x, kern, xh, kT, kT32, colnp, rown,
                                        blockcand, wta, n2h, out, bar);
}

// Round 6
// 204.886 us; speedup vs baseline: 2.4530x; 2.4530x over previous
//
#include <hip/hip_runtime.h>
#include <hip/hip_fp16.h>

#define OUTN 16384
#define BATCH 2048
#define DIM   256

typedef _Float16 half8 __attribute__((ext_vector_type(8)));
typedef float    floatx4 __attribute__((ext_vector_type(4)));
typedef unsigned long long u64;

__device__ __forceinline__ void gl2lds16(const void* g, void* l) {
    __builtin_amdgcn_global_load_lds(
        (const __attribute__((address_space(1))) void*)g,
        (__attribute__((address_space(3))) void*)l, 16, 0, 0);
}

// monotone float->uint map packed with column index (low 32): min(pack) = argmin
__device__ __forceinline__ u64 packkey(float v, int col) {
    unsigned u = __float_as_uint(v);
    u = (u & 0x80000000u) ? ~u : (u | 0x80000000u);
    return ((u64)u << 32) | (unsigned)col;
}
__device__ __forceinline__ float unpackval(u64 p) {
    unsigned u = (unsigned)(p >> 32);
    u = (u & 0x80000000u) ? (u & 0x7fffffffu) : ~u;
    return __uint_as_float(u);
}

// ---------------- P0 fused prep ----------------
// blocks [0,512): transpose kern -> kT (f16) + kT32 (fp32) + fp32 col-norm halves
// blocks [512,2560): x -> f16 + row norms
__global__ __launch_bounds__(256) void prep_all(
        const float* __restrict__ x, const float* __restrict__ kern,
        _Float16* __restrict__ xh, float* __restrict__ rown,
        _Float16* __restrict__ kT, float* __restrict__ kT32,
        float* __restrict__ colnp) {
    int blk = blockIdx.x, t = threadIdx.x;
    if (blk < 512) {
        __shared__ float tile[64][65];
        __shared__ float npart[4][64];
        int tx = t & 63, ty = t >> 6;
        int j0 = (blk >> 1) * 64;
        int dhalf = blk & 1, dbase = dhalf * 128;
        float nrm = 0.f;
        for (int pc = 0; pc < 2; pc++) {
            int dc = dbase + pc * 64;
            __syncthreads();
            for (int it = 0; it < 16; it++) {
                int d = dc + ty + it * 4;
                float v = kern[(size_t)d * OUTN + j0 + tx];
                tile[ty + it * 4][tx] = v;
                nrm = fmaf(v, v, nrm);
            }
            __syncthreads();
            for (int c = t; c < 512; c += 256) {   // 64j x 64d out, 8-elem chunks
                int j = c >> 3, o8 = (c & 7) * 8;
                half8 h; float vv[8];
                for (int u = 0; u < 8; u++) { vv[u] = tile[o8 + u][j]; h[u] = (_Float16)vv[u]; }
                *(half8*)&kT[(size_t)(j0 + j) * DIM + dc + o8] = h;
                float* kp = &kT32[(size_t)(j0 + j) * DIM + dc + o8];
                *(float4*)kp       = make_float4(vv[0], vv[1], vv[2], vv[3]);
                *(float4*)(kp + 4) = make_float4(vv[4], vv[5], vv[6], vv[7]);
            }
        }
        npart[ty][tx] = nrm;
        __syncthreads();
        if (t < 64)
            colnp[(size_t)dhalf * OUTN + j0 + t] =
                npart[0][t] + npart[1][t] + npart[2][t] + npart[3][t];
    } else {
        int b = blk - 512;                         // 2048 rows
        float v = x[b * DIM + t];
        xh[b * DIM + t] = (_Float16)v;
        float s = v * v;
        for (int off = 32; off; off >>= 1) s += __shfl_down(s, off, 64);
        __shared__ float wsum[4];
        if ((t & 63) == 0) wsum[t >> 6] = s;
        __syncthreads();
        if (t == 0) rown[b] = wsum[0] + wsum[1] + wsum[2] + wsum[3];
    }
}

// ---------------- P1: f16 MFMA GEMM -> f16 norms2 + per-(row,128col) top-2 candidates ----
__global__ __launch_bounds__(256) void gemm_norms(
        const _Float16* __restrict__ xh, const _Float16* __restrict__ kT,
        const float* __restrict__ rown, const float* __restrict__ colnp,
        _Float16* __restrict__ n2h, u64* __restrict__ blockcand) {
    __shared__ __align__(16) char smem[35328];
    _Float16* As = (_Float16*)smem;                // 128x64 f16, XOR-swizzled granules
    _Float16* Bs = (_Float16*)(smem + 16384);
    u64* cand = (u64*)smem;                        // 128 x stride-33 u64 (33792 B), after k-loop
    _Float16* nb = (_Float16*)smem;                // 128 x stride-136 f16 (34816 B), after cand
    float* rnl = (float*)(smem + 34816);           // 128 fp32 row norms
    int tid  = threadIdx.x;
    int col0 = blockIdx.x * 128;
    int row0 = blockIdx.y * 128;
    int wid = tid >> 6, lane = tid & 63;
    int wr = wid >> 1, wc = wid & 1;
    int l15 = lane & 15, l4 = lane >> 4;
    int xh7 = l15 & 7;

    if (tid < 128) rnl[tid] = rown[row0 + tid];

    floatx4 acc[4][4];
    for (int i = 0; i < 4; i++)
        for (int j = 0; j < 4; j++)
            acc[i][j] = (floatx4){0.f, 0.f, 0.f, 0.f};

    for (int kt = 0; kt < 4; kt++) {
        int k0 = kt * 64;
        for (int it = 0; it < 4; it++) {
            int chunk = it * 256 + tid;            // 1024 granules x 16B each tile
            int r = chunk >> 3, gg = chunk & 7;
            int ksw = (gg ^ (r & 7)) * 8;          // XOR-swizzled source granule
            gl2lds16(&xh[(size_t)(row0 + r) * DIM + k0 + ksw], &As[chunk * 8]);
            gl2lds16(&kT[(size_t)(col0 + r) * DIM + k0 + ksw], &Bs[chunk * 8]);
        }
        __syncthreads();
        for (int s = 0; s < 2; s++) {
            int g = s * 4 + l4;
            int sw = (g ^ xh7) * 8;
            half8 af[4], bf[4];
            for (int i = 0; i < 4; i++)
                af[i] = *(half8*)&As[(wr * 64 + i * 16 + l15) * 64 + sw];
            for (int j = 0; j < 4; j++)
                bf[j] = *(half8*)&Bs[(wc * 64 + j * 16 + l15) * 64 + sw];
            for (int i = 0; i < 4; i++)
                for (int j = 0; j < 4; j++)
                    acc[i][j] = __builtin_amdgcn_mfma_f32_16x16x32_f16(
                        af[i], bf[j], acc[i][j], 0, 0, 0);
        }
        __syncthreads();
    }

    float cn[4]; int oc[4];
    for (int j = 0; j < 4; j++) {
        oc[j] = col0 + wc * 64 + j * 16 + l15;
        cn[j] = colnp[oc[j]] + colnp[OUTN + oc[j]];
    }
    // candidates: key = coln - 2*dot (row-constant ||x||^2 dropped; per-row argmin unchanged)
    for (int i = 0; i < 4; i++) {
        for (int r = 0; r < 4; r++) {
            int row_l = wr * 64 + i * 16 + l4 * 4 + r;
            u64 best = ~0ull;
            for (int j = 0; j < 4; j++) {
                u64 pk = packkey(cn[j] - 2.0f * acc[i][j][r], oc[j]);
                if (pk < best) best = pk;
            }
            cand[row_l * 33 + wc * 16 + l15] = best;
        }
    }
    __syncthreads();
    if (tid < 128) {                               // per row: top-2 of 32 thread-mins
        u64 m1 = ~0ull, m2 = ~0ull;
        for (int s = 0; s < 32; s++) {
            u64 v = cand[tid * 33 + s];
            if (v < m1) { m2 = m1; m1 = v; }
            else if (v < m2) { m2 = v; }
        }
        size_t base = (size_t)(row0 + tid) * 256 + blockIdx.x * 2;
        blockcand[base]     = m1;
        blockcand[base + 1] = m2;
    }
    __syncthreads();                               // all cand reads done before nb overwrite

    // f16 norms2 through LDS -> half8 coalesced global stores
    for (int i = 0; i < 4; i++) {
        for (int r = 0; r < 4; r++) {
            int row_l = wr * 64 + i * 16 + l4 * 4 + r;
            float rn = rnl[row_l];
            for (int j = 0; j < 4; j++)
                nb[row_l * 136 + wc * 64 + j * 16 + l15] =
                    (_Float16)(rn + cn[j] - 2.0f * acc[i][j][r]);
        }
    }
    __syncthreads();
    for (int c = tid; c < 2048; c += 256) {        // 128 rows x 16 chunks of 8 f16
        int r = c >> 4, o8 = (c & 15) * 8;
        *(half8*)&n2h[(size_t)(row0 + r) * OUTN + col0 + o8] =
            *(half8*)&nb[r * 136 + o8];
    }
}

// ---------------- P2: candidate argmin (exact fp32, contiguous kT32) + fused finalize ----
__global__ __launch_bounds__(256) void refine_finalize(
        const u64* __restrict__ blockcand, const float* __restrict__ x,
        const float* __restrict__ kT32, const float* __restrict__ colnp,
        const _Float16* __restrict__ n2h, float* __restrict__ out) {
    int b = blockIdx.x, t = threadIdx.x;           // 2048 x 256
    __shared__ float xrow[DIM];
    __shared__ u64 red[256];
    __shared__ float colf[128];
    xrow[t] = x[b * DIM + t];
    if (t < 128) colf[t] = __expf(-0.125f * (float)(t * t));
    u64 e = blockcand[(size_t)b * 256 + t];
    red[t] = e;
    __syncthreads();
    for (int off = 128; off; off >>= 1) {
        if (t < off) { u64 o = red[t + off]; if (o < red[t]) red[t] = o; }
        __syncthreads();
    }
    float minv = unpackval(red[0]);
    __syncthreads();

    u64 pk = ~0ull;
    if (unpackval(e) <= minv + 0.125f) {           // superset of true winner (2x f16 err << delta)
        int j = (int)(e & 0xffffffffu);
        const float4* kr4 = (const float4*)(kT32 + (size_t)j * DIM);
        const float4* xr4 = (const float4*)xrow;
        float s0 = 0.f, s1 = 0.f, s2 = 0.f, s3 = 0.f;
        for (int q = 0; q < 64; q += 4) {
            float4 k0 = kr4[q],     x0 = xr4[q];
            float4 k1 = kr4[q + 1], x1 = xr4[q + 1];
            float4 k2 = kr4[q + 2], x2 = xr4[q + 2];
            float4 k3 = kr4[q + 3], x3 = xr4[q + 3];
            s0 = fmaf(k0.x, x0.x, fmaf(k0.y, x0.y, fmaf(k0.z, x0.z, fmaf(k0.w, x0.w, s0))));
            s1 = fmaf(k1.x, x1.x, fmaf(k1.y, x1.y, fmaf(k1.z, x1.z, fmaf(k1.w, x1.w, s1))));
            s2 = fmaf(k2.x, x2.x, fmaf(k2.y, x2.y, fmaf(k2.z, x2.z, fmaf(k2.w, x2.w, s2))));
            s3 = fmaf(k3.x, x3.x, fmaf(k3.y, x3.y, fmaf(k3.z, x3.z, fmaf(k3.w, x3.w, s3))));
        }
        float dot = (s0 + s1) + (s2 + s3);
        pk = packkey((colnp[j] + colnp[OUTN + j]) - 2.0f * dot, j);
    }
    red[t] = pk;
    __syncthreads();
    for (int off = 128; off; off >>= 1) {
        if (t < off) { u64 o = red[t + off]; if (o < red[t]) red[t] = o; }
        __syncthreads();
    }
    int w = (int)(red[0] & 0xffffffffu);
    int wrr = w >> 7, wcc = w & 127;

    // finalize: out = colf[|dr|]*colf[|dc|] * max(norms2,0); zero outside |dr|<=26 disk
    const _Float16* nrow = n2h + (size_t)b * OUTN;
    float* orow = out + (size_t)b * OUTN;
    for (int c = t; c < 2048; c += 256) {          // 128 grid-rows x 16 chunks of 8
        int gr = c >> 4, o8 = (c & 15) * 8;
        int dr = gr - wrr; if (dr < 0) dr = -dr;
        float4 r0 = {0.f, 0.f, 0.f, 0.f}, r1 = {0.f, 0.f, 0.f, 0.f};
        if (dr <= 26) {                            // exp(-0.125*27^2) ~ 1e-40: exact zero in fp32
            float rowf = colf[dr];
            half8 h = *(const half8*)&nrow[gr * 128 + o8];
            float res[8];
            for (int u = 0; u < 8; u++) {
                int dc = o8 + u - wcc; if (dc < 0) dc = -dc;
                res[u] = rowf * colf[dc] * fmaxf((float)h[u], 0.f);
            }
            r0 = make_float4(res[0], res[1], res[2], res[3]);
            r1 = make_float4(res[4], res[5], res[6], res[7]);
        }
        *(float4*)&orow[gr * 128 + o8]     = r0;
        *(float4*)&orow[gr * 128 + o8 + 4] = r1;
    }
}

extern "C" void kernel_launch(void* const* d_in, const int* in_sizes, int n_in,
                              void* d_out, int out_size, void* d_ws, size_t ws_size,
                              hipStream_t stream) {
    const float* x    = (const float*)d_in[0];   // (2048, 256) fp32
    const float* kern = (const float*)d_in[1];   // (256, 16384) fp32
    float* out = (float*)d_out;                  // (2048, 16384) fp32
    char* ws = (char*)d_ws;

    // ws (96 MB): xh 1MB@0 | kT 8MB@1M | kT32 16MB@9M | colnp 128K@25M | rown 8K |
    //             blockcand 4MB@26M | n2h 64MB@32M
    _Float16* xh   = (_Float16*)(ws);
    _Float16* kT   = (_Float16*)(ws + (1u << 20));
    float*    kT32 = (float*)(ws + (9u << 20));
    float*   colnp = (float*)(ws + (25u << 20));
    float*    rown = (float*)(ws + (25u << 20) + (128u << 10));
    u64* blockcand = (u64*)(ws + (26u << 20));
    _Float16*  n2h = (_Float16*)(ws + (32u << 20));

    prep_all<<<2560, 256, 0, stream>>>(x, kern, xh, rown, kT, kT32, colnp);
    gemm_norms<<<dim3(OUTN / 128, BATCH / 128), 256, 0, stream>>>(
        xh, kT, rown, colnp, n2h, blockcand);
    refine_finalize<<<BATCH, 256, 0, stream>>>(blockcand, x, kT32, colnp, n2h, out);
}